// Round 3
// baseline (158.563 us; speedup 1.0000x reference)
//
#include <hip/hip_runtime.h>
#include <math.h>

// HumanPoseModule: (BT,10,6) + (BT,6,6) f32 -> (BT,24,3) f32 axis-angle.
//
// R9: R7's root-free algebra + PERSISTENT GRID-STRIDE SOFTWARE PIPELINE.
// R7/R8 were load-latency-bound (VALU 40-44%, HBM 31%, no pipe saturated):
// each wave stalled ~500cy on L2/L3-resident input loads before ~400cy of
// compute. R8's in-thread ILP2 was serialized by the register allocator
// (VGPR stayed 32 -> both chains + their loads sequential). R9 instead
// double-buffers ACROSS loop iterations: 2048 blocks (8/CU, all resident),
// each 16-lane group walks BT/32768 elements; next element's 3x dwordx2
// loads are issued at the top of each iteration (pinned by sched_barrier)
// and consumed one iteration later -> load latency hides under compute,
// and the compiler cannot sink it into the dependency chain.
//
// Identity (R7): full[j] = root @ X_j, root orthonormal =>
// local[j] = X_parent^T @ X_j; joints 1,2,3: local = X_j; joint 0: root.
//
// Lane tables (byte-packed u64s; lane l = tid&15):
//   joints: {0,1,2,3,4,5,6,9,12,13,14,15,16,17,18,19}
//   srcj:   sel<<4|row  (sel 0 = glb row, 1 = ori row)
//   pl:     parent's lane within the 16-group (lanes 0-3 unused: direct)
// Ignored joints {7,8,10,11,20,21,22,23} -> zeros, written by lanes 0-7.

__device__ __forceinline__ void rot6d_v(float2 u0, float2 u1, float2 u2, float M[3][3]) {
    float a1x = u0.x, a1y = u0.y, a1z = u1.x;
    float a2x = u1.y, a2y = u2.x, a2z = u2.y;
    float r1 = __builtin_amdgcn_rsqf(a1x * a1x + a1y * a1y + a1z * a1z);
    float b1x = a1x * r1, b1y = a1y * r1, b1z = a1z * r1;
    float dt = b1x * a2x + b1y * a2y + b1z * a2z;
    float c2x = a2x - dt * b1x, c2y = a2y - dt * b1y, c2z = a2z - dt * b1z;
    float r2 = __builtin_amdgcn_rsqf(c2x * c2x + c2y * c2y + c2z * c2z);
    float b2x = c2x * r2, b2y = c2y * r2, b2z = c2z * r2;
    float b3x = b1y * b2z - b1z * b2y;
    float b3y = b1z * b2x - b1x * b2z;
    float b3z = b1x * b2y - b1y * b2x;
    M[0][0] = b1x; M[0][1] = b1y; M[0][2] = b1z;
    M[1][0] = b2x; M[1][1] = b2y; M[1][2] = b2z;
    M[2][0] = b3x; M[2][1] = b3y; M[2][2] = b3z;
}

// C = A^T @ B
__device__ __forceinline__ void matTmul(const float A[3][3], const float B[3][3], float C[3][3]) {
#pragma unroll
    for (int i = 0; i < 3; ++i)
#pragma unroll
        for (int j = 0; j < 3; ++j)
            C[i][j] = A[0][i] * B[0][j] + A[1][i] * B[1][j] + A[2][i] * B[2][j];
}

// atan2(y,x) for y >= 0, result in [0, pi]. Minimax atan poly on [0,1], err ~2e-8.
__device__ __forceinline__ float atan2_pos(float y, float x) {
    float ax = fabsf(x);
    float mx = fmaxf(y, ax);
    float mn = fminf(y, ax);
    float a = mn * __builtin_amdgcn_rcpf(mx);
    float s = a * a;
    float p = -0.0040540580f;
    p = fmaf(p, s, 0.0218612288f);
    p = fmaf(p, s, -0.0559098861f);
    p = fmaf(p, s, 0.0964200441f);
    p = fmaf(p, s, -0.1390853351f);
    p = fmaf(p, s, 0.1994653599f);
    p = fmaf(p, s, -0.3332985605f);
    p = fmaf(p, s, 0.9999993329f);
    float r = p * a;
    r = (y > ax) ? (1.5707963268f - r) : r;
    r = (x < 0.f) ? (3.1415926536f - r) : r;
    return r;
}

__device__ __forceinline__ void mat2aa(const float m[3][3], float* __restrict__ outp) {
    float m00 = m[0][0], m01 = m[0][1], m02 = m[0][2];
    float m10 = m[1][0], m11 = m[1][1], m12 = m[1][2];
    float m20 = m[2][0], m21 = m[2][1], m22 = m[2][2];
    float t0 = fmaxf(1.f + m00 + m11 + m22, 0.f);
    float t1 = fmaxf(1.f + m00 - m11 - m22, 0.f);
    float t2 = fmaxf(1.f - m00 + m11 - m22, 0.f);
    float t3 = fmaxf(1.f - m00 - m11 + m22, 0.f);
    // argmax over t == argmax over sqrt(t) (monotonic, same first-max ties)
    int idx = 0;
    float bt = t0;
    if (t1 > bt) { bt = t1; idx = 1; }
    if (t2 > bt) { bt = t2; idx = 2; }
    if (t3 > bt) { bt = t3; idx = 3; }
    float best = __builtin_amdgcn_sqrtf(bt);  // >= 1 always (sum of t == 4)
    float s1 = m21 - m12, s2 = m02 - m20, s3 = m10 - m01;
    float p1 = m10 + m01, p2 = m02 + m20, p3 = m12 + m21;
    float w = (idx == 0) ? bt : (idx == 1) ? s1 : (idx == 2) ? s2 : s3;
    float x = (idx == 0) ? s1 : (idx == 1) ? bt : (idx == 2) ? p1 : p2;
    float y = (idx == 0) ? s2 : (idx == 1) ? p1 : (idx == 2) ? bt : p3;
    float z = (idx == 0) ? s3 : (idx == 1) ? p2 : (idx == 2) ? p3 : bt;
    float inv = 0.5f * __builtin_amdgcn_rcpf(fmaxf(best, 0.1f));
    w *= inv; x *= inv; y *= inv; z *= inv;
    // unit quaternion: sin(half) == |v|, cos(half) == w
    float n = __builtin_amdgcn_sqrtf(x * x + y * y + z * z);
    float half = atan2_pos(n, w);
    float angle = 2.f * half;
    // angle < 1e-6 => ref's (0.5 - angle^2/48) rounds to 0.5 => inv_sh = 2
    float inv_sh = (angle < 1e-6f) ? 2.f : angle * __builtin_amdgcn_rcpf(n);
    outp[0] = x * inv_sh;
    outp[1] = y * inv_sh;
    outp[2] = z * inv_sh;
}

__global__ __launch_bounds__(256) void pose_kernel(const float* __restrict__ glb,
                                                   const float* __restrict__ ori,
                                                   float* __restrict__ out,
                                                   int BT, int stride) {
    int tid = blockIdx.x * 256 + threadIdx.x;
    int g = tid >> 4;   // 16-lane group id = first element index
    if (g >= BT) return;
    int l = tid & 15;

    // byte-packed per-lane tables
    const unsigned long long OUT3_LO = 0x1B120F0C09060300ULL;  // joint*3, lanes 0-7
    const unsigned long long OUT3_HI = 0x393633302D2A2724ULL;  // lanes 8-15
    const unsigned long long SRCJ_LO = 0x0403121102010010ULL;
    const unsigned long long SRCJ_HI = 0x1514090813070605ULL;
    const unsigned long long PL_LO   = 0x0603020100000000ULL;  // parent lane, lanes 4-7
    const unsigned long long PL_HI   = 0x0D0C0A0908070707ULL;  // lanes 8-15
    const unsigned long long IGN3    = 0x45423F3C211E1815ULL;  // ignored joint*3, lanes 0-7

    int sh = (l & 7) * 8;
    int out3 = (int)(((l < 8 ? OUT3_LO : OUT3_HI) >> sh) & 0xFF);
    int srcj = (int)(((l < 8 ? SRCJ_LO : SRCJ_HI) >> sh) & 0xFF);
    int pl   = (int)(((l < 8 ? PL_LO   : PL_HI)   >> sh) & 0xFF);
    int z    = (int)((IGN3 >> sh) & 0xFF);

    int row6 = (srcj & 15) * 6;
    bool from_ori = (srcj & 0x10) != 0;
    const float* sb = from_ori ? ori : glb;
    int per = from_ori ? 36 : 60;

    // incremental pointers: one 64-bit add per iteration, no per-iter muls
    const float* src = sb + (size_t)g * per + row6;     // 8B-aligned
    size_t sstep = (size_t)stride * per;                // floats
    float* po = out + (size_t)g * 72;
    size_t ostep = (size_t)stride * 72;

    // prologue: load element g
    const float2* s2 = (const float2*)src;
    float2 cu0 = s2[0], cu1 = s2[1], cu2 = s2[2];

    for (int e = g; e < BT; e += stride) {
        // ---- prefetch next element (issued before any use of cu*) ----
        bool more = (e + stride) < BT;
        const float* nsrc = src + (more ? sstep : 0);   // clamp: re-read cur if last
        const float2* n2 = (const float2*)nsrc;
        float2 nu0 = n2[0], nu1 = n2[1], nu2 = n2[2];
        __builtin_amdgcn_sched_barrier(0);   // pin prefetch issue above compute

        // ---- compute current element ----
        float X[3][3];
        rot6d_v(cu0, cu1, cu2, X);

        float Xp[3][3];
        {
            const float* xf = &X[0][0];
            float* pf = &Xp[0][0];
#pragma unroll
            for (int q = 0; q < 9; ++q) pf[q] = __shfl(xf[q], pl, 16);
        }

        float L[3][3];
        matTmul(Xp, X, L);
#pragma unroll
        for (int i = 0; i < 3; ++i)
#pragma unroll
            for (int j = 0; j < 3; ++j)
                L[i][j] = (l < 4) ? X[i][j] : L[i][j];

        mat2aa(L, po + out3);

        if (l < 8) {
            float* zp = po + z;
            zp[0] = 0.f; zp[1] = 0.f; zp[2] = 0.f;
        }

        // ---- rotate buffers / advance ----
        src = nsrc;
        po += ostep;
        cu0 = nu0; cu1 = nu1; cu2 = nu2;
    }
}

extern "C" void kernel_launch(void* const* d_in, const int* in_sizes, int n_in,
                              void* d_out, int out_size, void* d_ws, size_t ws_size,
                              hipStream_t stream) {
    const float* glb = (const float*)d_in[0];   // (BT,10,6) f32
    const float* ori = (const float*)d_in[1];   // (BT,6,6)  f32
    float* out = (float*)d_out;                 // (BT,24,3) f32
    int BT = in_sizes[0] / 60;
    // persistent-ish: 2048 blocks = 8 blocks/CU x 256 CUs, all resident.
    long long groups_needed = (long long)BT;          // 16 lanes per element
    int grid = 2048;
    long long max_grid = (groups_needed * 16 + 255) / 256;
    if (max_grid < grid) grid = (int)max_grid;
    int stride = grid * 16;                           // elements per sweep
    pose_kernel<<<grid, 256, 0, stream>>>(glb, ori, out, BT, stride);
}

// Round 4
// 150.548 us; speedup vs baseline: 1.0532x; 1.0532x over previous
//
#include <hip/hip_runtime.h>
#include <math.h>

// HumanPoseModule: (BT,10,6) + (BT,6,6) f32 -> (BT,24,3) f32 axis-angle.
//
// R10: R7's root-free algebra + LDS-STAGED INPUTS.
// R7 was latency-bound with ~26us of un-hidden memory latency: each lane
// issued 3 scattered 8B global loads (24B-strided, mixed glb/ori), so each
// wave VMEM instruction fragmented into ~10-20 transactions -> deep memory
// queues, ~2700cy effective span per wave, VALUBusy capped at 44%.
// R8 (in-thread ILP2) was serialized by regalloc; R9 (persistent pipeline)
// regressed (sched_barrier too strong, fewer WGs). R10 instead stages each
// block's 16 elements (6KB) into LDS with 384 fully-coalesced float4 loads,
// then computes from LDS (ds_read_b64 ~120cy, ~2-way conflicts = free).
// The single global wait per block sits behind __syncthreads and is hidden
// by ~8 resident blocks/CU; the per-wave critical chain loses the ~900cy
// global-load stall.
//
// Identity (R7): full[j] = root @ X_j, root orthonormal =>
// local[j] = X_parent^T @ X_j; joints 1,2,3: local = X_j; joint 0: root.
//
// Lane tables (byte-packed u64s; lane l = tid&15):
//   joints: {0,1,2,3,4,5,6,9,12,13,14,15,16,17,18,19}
//   srcj:   sel<<4|row  (sel 0 = glb row, 1 = ori row)
//   pl:     parent's lane within the 16-group (lanes 0-3 unused: direct)
// Ignored joints {7,8,10,11,20,21,22,23} -> zeros, written by lanes 0-7.

__device__ __forceinline__ void rot6d_v(float2 u0, float2 u1, float2 u2, float M[3][3]) {
    float a1x = u0.x, a1y = u0.y, a1z = u1.x;
    float a2x = u1.y, a2y = u2.x, a2z = u2.y;
    float r1 = __builtin_amdgcn_rsqf(a1x * a1x + a1y * a1y + a1z * a1z);
    float b1x = a1x * r1, b1y = a1y * r1, b1z = a1z * r1;
    float dt = b1x * a2x + b1y * a2y + b1z * a2z;
    float c2x = a2x - dt * b1x, c2y = a2y - dt * b1y, c2z = a2z - dt * b1z;
    float r2 = __builtin_amdgcn_rsqf(c2x * c2x + c2y * c2y + c2z * c2z);
    float b2x = c2x * r2, b2y = c2y * r2, b2z = c2z * r2;
    float b3x = b1y * b2z - b1z * b2y;
    float b3y = b1z * b2x - b1x * b2z;
    float b3z = b1x * b2y - b1y * b2x;
    M[0][0] = b1x; M[0][1] = b1y; M[0][2] = b1z;
    M[1][0] = b2x; M[1][1] = b2y; M[1][2] = b2z;
    M[2][0] = b3x; M[2][1] = b3y; M[2][2] = b3z;
}

// C = A^T @ B
__device__ __forceinline__ void matTmul(const float A[3][3], const float B[3][3], float C[3][3]) {
#pragma unroll
    for (int i = 0; i < 3; ++i)
#pragma unroll
        for (int j = 0; j < 3; ++j)
            C[i][j] = A[0][i] * B[0][j] + A[1][i] * B[1][j] + A[2][i] * B[2][j];
}

// atan2(y,x) for y >= 0, result in [0, pi]. Minimax atan poly on [0,1], err ~2e-8.
__device__ __forceinline__ float atan2_pos(float y, float x) {
    float ax = fabsf(x);
    float mx = fmaxf(y, ax);
    float mn = fminf(y, ax);
    float a = mn * __builtin_amdgcn_rcpf(mx);
    float s = a * a;
    float p = -0.0040540580f;
    p = fmaf(p, s, 0.0218612288f);
    p = fmaf(p, s, -0.0559098861f);
    p = fmaf(p, s, 0.0964200441f);
    p = fmaf(p, s, -0.1390853351f);
    p = fmaf(p, s, 0.1994653599f);
    p = fmaf(p, s, -0.3332985605f);
    p = fmaf(p, s, 0.9999993329f);
    float r = p * a;
    r = (y > ax) ? (1.5707963268f - r) : r;
    r = (x < 0.f) ? (3.1415926536f - r) : r;
    return r;
}

__device__ __forceinline__ void mat2aa(const float m[3][3], float* __restrict__ outp) {
    float m00 = m[0][0], m01 = m[0][1], m02 = m[0][2];
    float m10 = m[1][0], m11 = m[1][1], m12 = m[1][2];
    float m20 = m[2][0], m21 = m[2][1], m22 = m[2][2];
    float t0 = fmaxf(1.f + m00 + m11 + m22, 0.f);
    float t1 = fmaxf(1.f + m00 - m11 - m22, 0.f);
    float t2 = fmaxf(1.f - m00 + m11 - m22, 0.f);
    float t3 = fmaxf(1.f - m00 - m11 + m22, 0.f);
    // argmax over t == argmax over sqrt(t) (monotonic, same first-max ties)
    int idx = 0;
    float bt = t0;
    if (t1 > bt) { bt = t1; idx = 1; }
    if (t2 > bt) { bt = t2; idx = 2; }
    if (t3 > bt) { bt = t3; idx = 3; }
    float best = __builtin_amdgcn_sqrtf(bt);  // >= 1 always (sum of t == 4)
    float s1 = m21 - m12, s2 = m02 - m20, s3 = m10 - m01;
    float p1 = m10 + m01, p2 = m02 + m20, p3 = m12 + m21;
    float w = (idx == 0) ? bt : (idx == 1) ? s1 : (idx == 2) ? s2 : s3;
    float x = (idx == 0) ? s1 : (idx == 1) ? bt : (idx == 2) ? p1 : p2;
    float y = (idx == 0) ? s2 : (idx == 1) ? p1 : (idx == 2) ? bt : p3;
    float z = (idx == 0) ? s3 : (idx == 1) ? p2 : (idx == 2) ? p3 : bt;
    float inv = 0.5f * __builtin_amdgcn_rcpf(fmaxf(best, 0.1f));
    w *= inv; x *= inv; y *= inv; z *= inv;
    // unit quaternion: sin(half) == |v|, cos(half) == w
    float n = __builtin_amdgcn_sqrtf(x * x + y * y + z * z);
    float half = atan2_pos(n, w);
    float angle = 2.f * half;
    // angle < 1e-6 => ref's (0.5 - angle^2/48) rounds to 0.5 => inv_sh = 2
    float inv_sh = (angle < 1e-6f) ? 2.f : angle * __builtin_amdgcn_rcpf(n);
    outp[0] = x * inv_sh;
    outp[1] = y * inv_sh;
    outp[2] = z * inv_sh;
}

__global__ __launch_bounds__(256) void pose_kernel(const float* __restrict__ glb,
                                                   const float* __restrict__ ori,
                                                   float* __restrict__ out, int BT) {
    // one block = 16 elements; LDS layout: [glb 16x60 | ori 16x36] floats
    __shared__ float lds[16 * 60 + 16 * 36];   // 1536 floats = 6 KB

    int t = threadIdx.x;
    int base = blockIdx.x * 16;                 // first element of this block
    int nelem = BT - base;
    if (nelem > 16) nelem = 16;

    // ---- stage: 240 glb float4 + 144 ori float4, fully coalesced ----
    {
        float4* l4 = (float4*)lds;              // glb at f4[0..240), ori at f4[240..384)
        const float4* g4 = (const float4*)glb + (size_t)base * 15;  // 60 f = 15 f4
        const float4* o4 = (const float4*)ori + (size_t)base * 9;   // 36 f = 9 f4
        int ng = nelem * 15, no = nelem * 9;
#pragma unroll
        for (int i = t; i < 384; i += 256) {
            if (i < 240) {
                if (i < ng) l4[i] = g4[i];
            } else {
                int j = i - 240;
                if (j < no) l4[240 + j] = o4[j];
            }
        }
    }
    __syncthreads();

    int eloc = t >> 4;
    int g = base + eloc;
    int l = t & 15;

    // byte-packed per-lane tables
    const unsigned long long OUT3_LO = 0x1B120F0C09060300ULL;  // joint*3, lanes 0-7
    const unsigned long long OUT3_HI = 0x393633302D2A2724ULL;  // lanes 8-15
    const unsigned long long SRCJ_LO = 0x0403121102010010ULL;
    const unsigned long long SRCJ_HI = 0x1514090813070605ULL;
    const unsigned long long PL_LO   = 0x0603020100000000ULL;  // parent lane, lanes 4-7
    const unsigned long long PL_HI   = 0x0D0C0A0908070707ULL;  // lanes 8-15
    const unsigned long long IGN3    = 0x45423F3C211E1815ULL;  // ignored joint*3, lanes 0-7

    int sh = (l & 7) * 8;
    int out3 = (int)(((l < 8 ? OUT3_LO : OUT3_HI) >> sh) & 0xFF);
    int srcj = (int)(((l < 8 ? SRCJ_LO : SRCJ_HI) >> sh) & 0xFF);
    int pl   = (int)(((l < 8 ? PL_LO   : PL_HI)   >> sh) & 0xFF);

    // own X = rot6d(src row) read from LDS (ds_read_b64 x3, ~2-way banks)
    int row6 = (srcj & 15) * 6;
    const float* src = (srcj & 0x10) ? (lds + 960 + eloc * 36 + row6)
                                     : (lds + eloc * 60 + row6);
    const float2* s2 = (const float2*)src;      // 8B-aligned (24B-multiple offsets)
    float2 u0 = s2[0], u1 = s2[1], u2 = s2[2];

    float X[3][3];
    rot6d_v(u0, u1, u2, X);

    // parent's X from the parent's lane (wave-synchronous, 16-lane groups)
    float Xp[3][3];
    {
        const float* xf = &X[0][0];
        float* pf = &Xp[0][0];
#pragma unroll
        for (int k = 0; k < 9; ++k) pf[k] = __shfl(xf[k], pl, 16);
    }

    // local = Xp^T @ X; lanes 0-3: local = X (parent is root / joint 0 is root)
    float L[3][3];
    matTmul(Xp, X, L);
#pragma unroll
    for (int i = 0; i < 3; ++i)
#pragma unroll
        for (int j = 0; j < 3; ++j)
            L[i][j] = (l < 4) ? X[i][j] : L[i][j];

    if (g < BT) {
        float* oute = out + (size_t)g * 72;
        mat2aa(L, oute + out3);

        // ignored joints -> exact zeros (lanes 0-7, one each)
        if (l < 8) {
            int z = (int)((IGN3 >> sh) & 0xFF);
            float* zp = oute + z;
            zp[0] = 0.f; zp[1] = 0.f; zp[2] = 0.f;
        }
    }
}

extern "C" void kernel_launch(void* const* d_in, const int* in_sizes, int n_in,
                              void* d_out, int out_size, void* d_ws, size_t ws_size,
                              hipStream_t stream) {
    const float* glb = (const float*)d_in[0];   // (BT,10,6) f32
    const float* ori = (const float*)d_in[1];   // (BT,6,6)  f32
    float* out = (float*)d_out;                 // (BT,24,3) f32
    int BT = in_sizes[0] / 60;
    int grid = (BT + 15) / 16;                  // 16 elements per 256-thread block
    pose_kernel<<<grid, 256, 0, stream>>>(glb, ori, out, BT);
}